// Round 4
// baseline (179.034 us; speedup 1.0000x reference)
//
#include <hip/hip_runtime.h>
#include <cstdint>
#include <cstddef>

// Problem constants (MaskedCrossAttention_27986006901343)
#define BB    4
#define TQ    2048
#define DIM   1024
#define TKV   16
#define NLAT  64
#define DLAT  1024
#define HEADS 8
#define DHEAD 64
#define LN_EPS 1e-5f
#define NKV   (TKV*NLAT)      // 1024 latents per batch
#define HD    (HEADS*DHEAD)   // 512

typedef unsigned short u16;
typedef __bf16 bf16x8 __attribute__((ext_vector_type(8)));
typedef float  f32x4  __attribute__((ext_vector_type(4)));

__device__ __forceinline__ u16 f2bf(float f) {      // RNE f32->bf16
    unsigned u = __builtin_bit_cast(unsigned, f);
    u += 0x7fffu + ((u >> 16) & 1u);
    return (u16)(u >> 16);
}
__device__ __forceinline__ void gl_lds16(const void* g, void* l) {
    __builtin_amdgcn_global_load_lds(
        (const __attribute__((address_space(1))) void*)g,
        (__attribute__((address_space(3))) void*)l, 16, 0, 0);
}

// ===========================================================================
// prep_k: fused qtime + LN(qo)->bf16 + cvt(kvo)->bf16 + 3 weight transposes.
// ===========================================================================
__device__ __forceinline__ void transpose_dev(const float* __restrict__ W,
                                              u16* __restrict__ Wt,
                                              int K, int N, int n0, int k0,
                                              float (*tile)[33]) {
    int t = threadIdx.x;
    int r = t >> 3, c4 = (t & 7) * 4;
    float4 v = *(const float4*)&W[(size_t)(k0 + r) * N + n0 + c4];
    tile[r][c4 + 0] = v.x; tile[r][c4 + 1] = v.y;
    tile[r][c4 + 2] = v.z; tile[r][c4 + 3] = v.w;
    __syncthreads();
    uint2 pk;
    pk.x = (unsigned)f2bf(tile[c4 + 0][r]) | ((unsigned)f2bf(tile[c4 + 1][r]) << 16);
    pk.y = (unsigned)f2bf(tile[c4 + 2][r]) | ((unsigned)f2bf(tile[c4 + 3][r]) << 16);
    *(uint2*)&Wt[(size_t)(n0 + r) * K + k0 + c4] = pk;
}

__global__ __launch_bounds__(256) void prep_k(
    const float* __restrict__ qo, const float* __restrict__ kvo,
    const uint8_t* __restrict__ media,
    const float* __restrict__ ln_g, const float* __restrict__ ln_b,
    const float* __restrict__ Wq, const float* __restrict__ Wkv,
    const float* __restrict__ Wout,
    int* __restrict__ qt, u16* __restrict__ Aq, u16* __restrict__ Akv,
    u16* __restrict__ Wqt, u16* __restrict__ Wkvt, u16* __restrict__ Woutt) {
    __shared__ int part[256];
    __shared__ int cnt_sh;
    __shared__ float sh[8];
    __shared__ float mu_s, rs_s;
    __shared__ float tile[32][33];
    int blk = blockIdx.x, t = threadIdx.x;

    if (blk < 4) {                    // ---- qtime (media dtype sniffed) ----
        int b = blk;
        int c = 0;
        for (int i = 0; i < 32; ++i) c += (media[t * 32 + i] != 0);
        part[t] = c;
        __syncthreads();
        if (t == 0) { int s = 0; for (int i = 0; i < 256; ++i) s += part[i]; cnt_sh = s; }
        __syncthreads();
        bool is_u8 = (cnt_sh >= 48);
        int vals[8];
        for (int i = 0; i < 8; ++i) {
            int idx = t * 8 + i;
            int m;
            if (is_u8) m = (media[(size_t)b * TQ + idx] != 0) ? 1 : 0;
            else       m = (((const uint32_t*)media)[(size_t)b * TQ + idx] != 0u) ? 1 : 0;
            vals[i] = m;
        }
        int loc = 0;
        for (int i = 0; i < 8; ++i) loc += vals[i];
        __syncthreads();
        part[t] = loc;
        __syncthreads();
        int pre = 0;
        for (int i = 0; i < t; ++i) pre += part[i];
        int run = pre;
        for (int i = 0; i < 8; ++i) {
            run += vals[i];
            qt[(size_t)b * TQ + t * 8 + i] = run;
        }
    } else if (blk < 4 + BB * TQ) {   // ---- LayerNorm + bf16 ----
        int row = blk - 4;
        float4 v = *(const float4*)(qo + (size_t)row * DIM + t * 4);
        float s  = v.x + v.y + v.z + v.w;
        float ss = v.x * v.x + v.y * v.y + v.z * v.z + v.w * v.w;
        for (int off = 32; off; off >>= 1) { s += __shfl_down(s, off); ss += __shfl_down(ss, off); }
        if ((t & 63) == 0) { sh[(t >> 6) * 2] = s; sh[(t >> 6) * 2 + 1] = ss; }
        __syncthreads();
        if (t == 0) {
            float S  = sh[0] + sh[2] + sh[4] + sh[6];
            float SS = sh[1] + sh[3] + sh[5] + sh[7];
            float m  = S * (1.0f / DIM);
            mu_s = m;
            rs_s = rsqrtf(SS * (1.0f / DIM) - m * m + LN_EPS);
        }
        __syncthreads();
        float mu = mu_s, rs = rs_s;
        float4 gv = *(const float4*)(ln_g + t * 4);
        float4 bv = *(const float4*)(ln_b + t * 4);
        float a0 = (v.x - mu) * rs * gv.x + bv.x;
        float a1 = (v.y - mu) * rs * gv.y + bv.y;
        float a2 = (v.z - mu) * rs * gv.z + bv.z;
        float a3 = (v.w - mu) * rs * gv.w + bv.w;
        uint2 pk;
        pk.x = (unsigned)f2bf(a0) | ((unsigned)f2bf(a1) << 16);
        pk.y = (unsigned)f2bf(a2) | ((unsigned)f2bf(a3) << 16);
        *(uint2*)(Aq + (size_t)row * DIM + t * 4) = pk;
    } else if (blk < 4 + BB * TQ + 2048) {   // ---- kvo f32->bf16 ----
        size_t i = (size_t)(blk - 4 - BB * TQ) * 256 + t;
        float4 a = ((const float4*)kvo)[i * 2];
        float4 b = ((const float4*)kvo)[i * 2 + 1];
        uint4 pk;
        pk.x = (unsigned)f2bf(a.x) | ((unsigned)f2bf(a.y) << 16);
        pk.y = (unsigned)f2bf(a.z) | ((unsigned)f2bf(a.w) << 16);
        pk.z = (unsigned)f2bf(b.x) | ((unsigned)f2bf(b.y) << 16);
        pk.w = (unsigned)f2bf(b.z) | ((unsigned)f2bf(b.w) << 16);
        ((uint4*)Akv)[i] = pk;
    } else if (blk < 10244 + 512) {   // ---- Wq^T ----
        int id = blk - 10244;
        transpose_dev(Wq, Wqt, DIM, HD, (id & 15) * 32, (id >> 4) * 32, tile);
    } else if (blk < 10756 + 1024) {  // ---- Wkv^T ----
        int id = blk - 10756;
        transpose_dev(Wkv, Wkvt, DLAT, 2 * HD, (id & 31) * 32, (id >> 5) * 32, tile);
    } else {                          // ---- Wout^T ----
        int id = blk - 11780;
        transpose_dev(Wout, Woutt, HD, DIM, (id & 31) * 32, (id >> 5) * 32, tile);
    }
}

// ===========================================================================
// bf16 MFMA GEMM body: C = A @ Bt^T * outscale.
// 128x64 tile (was 128x128): halves per-block work, doubles grid ->
// 4 blocks/CU co-residency to hide the 2-phase barrier drain (m114 overlap).
// BK=32, 4 waves (2x2: 64 rows x 32 cols each), global_load_lds staging.
// LDS: As 8KB x2 + Bs 4KB x2 = 24KB.
// ===========================================================================
template <typename CT>
__device__ __forceinline__ void gemm_body(const u16* __restrict__ A,
                                          const u16* __restrict__ Bt,
                                          CT* __restrict__ C,
                                          int M, int N, int K, float outscale,
                                          int bx, int by,
                                          u16* As0, u16* Bs0, u16* As1, u16* Bs1) {
    int t = threadIdx.x;
    int lane = t & 63, w = t >> 6;
    int wr = w >> 1, wc = w & 1;
    int fr = lane & 15, fg = lane >> 4;
    int row0 = by * 128, col0 = bx * 64;

    const u16* Ag = A  + (size_t)(row0 + (t >> 2)) * K + (t & 3) * 8;
    const u16* Bg = Bt + (size_t)(col0 + (t >> 2)) * K + (t & 3) * 8;
    size_t rstr = (size_t)64 * K;

    int aoff = (wr * 64 + fr) * 32 + fg * 8;   // u16 index into As
    int boff = (wc * 32 + fr) * 32 + fg * 8;   // u16 index into Bs

    f32x4 acc[4][2];
#pragma unroll
    for (int mi = 0; mi < 4; ++mi)
#pragma unroll
        for (int ni = 0; ni < 2; ++ni) acc[mi][ni] = (f32x4){0.f, 0.f, 0.f, 0.f};

    auto stage = [&](u16* Asb, u16* Bsb, int k0) {
        char* al = (char*)Asb + w * 1024;
        char* bl = (char*)Bsb + w * 1024;
        gl_lds16(Ag + k0,        al);
        gl_lds16(Ag + k0 + rstr, al + 4096);
        gl_lds16(Bg + k0,        bl);
    };
    auto compute = [&](const u16* Asb, const u16* Bsb) {
        bf16x8 af[4], bfv[2];
#pragma unroll
        for (int mi = 0; mi < 4; ++mi) af[mi]  = *(const bf16x8*)(Asb + aoff + mi * 512);
#pragma unroll
        for (int ni = 0; ni < 2; ++ni) bfv[ni] = *(const bf16x8*)(Bsb + boff + ni * 512);
#pragma unroll
        for (int mi = 0; mi < 4; ++mi)
#pragma unroll
            for (int ni = 0; ni < 2; ++ni)
                acc[mi][ni] = __builtin_amdgcn_mfma_f32_16x16x32_bf16(
                    af[mi], bfv[ni], acc[mi][ni], 0, 0, 0);
    };

    int nt = K >> 5;
    stage(As0, Bs0, 0);
    __syncthreads();
    for (int it = 0; it < nt; it += 2) {
        stage(As1, Bs1, (it + 1) << 5);
        compute(As0, Bs0);
        __syncthreads();
        if (it + 2 < nt) stage(As0, Bs0, (it + 2) << 5);
        compute(As1, Bs1);
        __syncthreads();
    }

#pragma unroll
    for (int mi = 0; mi < 4; ++mi) {
        int r0 = row0 + wr * 64 + mi * 16 + fg * 4;
#pragma unroll
        for (int ni = 0; ni < 2; ++ni) {
            int c = col0 + wc * 32 + ni * 16 + fr;
#pragma unroll
            for (int j = 0; j < 4; ++j) {
                float val = acc[mi][ni][j] * outscale;
                if constexpr (sizeof(CT) == 2) C[(size_t)(r0 + j) * N + c] = f2bf(val);
                else                           C[(size_t)(r0 + j) * N + c] = val;
            }
        }
    }
}

// Fused q-proj + kv-proj: 1024 blocks (4/CU).
__global__ __launch_bounds__(256) void proj_k(
    const u16* __restrict__ Aq,  const u16* __restrict__ Wqt,  u16* __restrict__ qb,
    const u16* __restrict__ Akv, const u16* __restrict__ Wkvt, u16* __restrict__ kvb) {
    __shared__ u16 As0[4096], As1[4096], Bs0[2048], Bs1[2048];
    int id = blockIdx.x;
    if (id < 512) {   // q-proj: M=8192 (by<64), N=512 (bx<8)
        gemm_body<u16>(Aq, Wqt, qb, BB * TQ, HD, DIM, 0.125f, id & 7, id >> 3,
                       As0, Bs0, As1, Bs1);
    } else {          // kv-proj: M=4096 (by<32), N=1024 (bx<16)
        id -= 512;
        gemm_body<u16>(Akv, Wkvt, kvb, BB * NKV, 2 * HD, DLAT, 1.0f, id & 15, id >> 4,
                       As0, Bs0, As1, Bs1);
    }
}

// out-proj: M=8192 (by<64), N=1024 (bx<16) -> 1024 blocks (4/CU).
__global__ __launch_bounds__(256) void out_k(
    const u16* __restrict__ aob, const u16* __restrict__ Woutt, float* __restrict__ out) {
    __shared__ u16 As0[4096], As1[4096], Bs0[2048], Bs1[2048];
    int id = blockIdx.x;
    gemm_body<float>(aob, Woutt, out, BB * TQ, DIM, HD, 1.0f, id & 15, id >> 4,
                     As0, Bs0, As1, Bs1);
}

// ===========================================================================
// MFMA masked cross attention (round-3 proven). 16 q-rows x head x batch per
// block; QK^T + PV via mfma_16x16x32_bf16; XOR-swizzled LDS.
// ===========================================================================
__global__ __launch_bounds__(256) void attn_k(
    const u16* __restrict__ q,    // (B*TQ, 512) bf16, pre-scaled by 0.125
    const u16* __restrict__ kv,   // (B*NKV, 1024) bf16: k [0,512), v [512,1024)
    const int* __restrict__ qt,
    u16* __restrict__ ao) {       // (B*TQ, 512) bf16
    __shared__ u16 Ks[4096];      // swizzled [64][64]
    __shared__ u16 VT[4096];      // swizzled [64 d][64 lat]
    __shared__ u16 Ps[1024];      // swizzled [16][64]
    __shared__ float redm[4][16], reds[4][16];
    int i0 = blockIdx.x * 16;
    int h  = blockIdx.y;
    int b  = blockIdx.z;
    int t  = threadIdx.x;
    int lane = t & 63, w = t >> 6;
    int fr = lane & 15, fg = lane >> 4;

    int t0 = qt[(size_t)b * TQ + i0];
    if (t0 == 0) {
        int row = t >> 4, c = (t & 15) * 4;
        *(uint2*)&ao[((size_t)(b * TQ + i0 + row)) * HD + h * DHEAD + c] = make_uint2(0, 0);
        return;
    }
    int j0 = (t0 - 1) * 64;

    {   // stage K (swizzled row-major) + V (transposed, swizzled)
        int j = t >> 2, c16 = (t & 3) * 16;
        const u16* kvrow = kv + ((size_t)(b * NKV + j0 + j)) * (2 * HD) + h * DHEAD;
        uint4 k0v = *(const uint4*)(kvrow + c16);
        uint4 k1v = *(const uint4*)(kvrow + c16 + 8);
        uint4 v0v = *(const uint4*)(kvrow + HD + c16);
        uint4 v1v = *(const uint4*)(kvrow + HD + c16 + 8);
        int kb = j * 128 + c16 * 2;
        int swz = (j & 7) << 4;
        *(uint4*)((char*)Ks + ((kb)      ^ swz)) = k0v;
        *(uint4*)((char*)Ks + ((kb + 16) ^ swz)) = k1v;
        const u16* ve0 = (const u16*)&v0v;
        const u16* ve1 = (const u16*)&v1v;
#pragma unroll
        for (int e = 0; e < 8; ++e) {
            int d0 = c16 + e, d1 = c16 + 8 + e;
            *(u16*)((char*)VT + ((d0 * 128 + j * 2) ^ ((d0 & 7) << 4))) = ve0[e];
            *(u16*)((char*)VT + ((d1 * 128 + j * 2) ^ ((d1 & 7) << 4))) = ve1[e];
        }
    }
    const u16* qrow = q + ((size_t)(b * TQ + i0 + fr)) * HD + h * DHEAD + fg * 8;
    bf16x8 aq0 = *(const bf16x8*)(qrow);
    bf16x8 aq1 = *(const bf16x8*)(qrow + 32);
    __syncthreads();

    // QK^T: wave w computes S[16][w*16..w*16+16)
    int r = w * 16 + fr;
    bf16x8 bk0 = *(const bf16x8*)((char*)Ks + ((r * 128 + fg * 16)      ^ ((r & 7) << 4)));
    bf16x8 bk1 = *(const bf16x8*)((char*)Ks + ((r * 128 + 64 + fg * 16) ^ ((r & 7) << 4)));
    f32x4 s = (f32x4){0.f, 0.f, 0.f, 0.f};
    s = __builtin_amdgcn_mfma_f32_16x16x32_bf16(aq0, bk0, s, 0, 0, 0);
    s = __builtin_amdgcn_mfma_f32_16x16x32_bf16(aq1, bk1, s, 0, 0, 0);

    // softmax over 64 cols (4 waves x 16): intra-wave shfl + LDS cross-wave
    float mx[4];
#pragma unroll
    for (int j = 0; j < 4; ++j) {
        float m = s[j];
        for (int off = 1; off < 16; off <<= 1) m = fmaxf(m, __shfl_xor(m, off));
        mx[j] = m;
        redm[w][fg * 4 + j] = m;
    }
    __syncthreads();
    float p[4];
#pragma unroll
    for (int j = 0; j < 4; ++j) {
        int row = fg * 4 + j;
        float M = fmaxf(fmaxf(redm[0][row], redm[1][row]), fmaxf(redm[2][row], redm[3][row]));
        p[j] = __expf(s[j] - M);
        float sm = p[j];
        for (int off = 1; off < 16; off <<= 1) sm += __shfl_xor(sm, off);
        reds[w][row] = sm;
    }
    __syncthreads();
#pragma unroll
    for (int j = 0; j < 4; ++j) {
        int row = fg * 4 + j;
        float S = reds[0][row] + reds[1][row] + reds[2][row] + reds[3][row];
        u16 pb = f2bf(p[j] / S);
        *(u16*)((char*)Ps + ((row * 128 + (w * 16 + fr) * 2) ^ ((row & 7) << 4))) = pb;
    }
    __syncthreads();

    // PV: wave w computes O[16][w*16..w*16+16)
    bf16x8 pa0 = *(const bf16x8*)((char*)Ps + ((fr * 128 + fg * 16)      ^ ((fr & 7) << 4)));
    bf16x8 pa1 = *(const bf16x8*)((char*)Ps + ((fr * 128 + 64 + fg * 16) ^ ((fr & 7) << 4)));
    int d = w * 16 + fr;
    bf16x8 bv0 = *(const bf16x8*)((char*)VT + ((d * 128 + fg * 16)      ^ ((d & 7) << 4)));
    bf16x8 bv1 = *(const bf16x8*)((char*)VT + ((d * 128 + 64 + fg * 16) ^ ((d & 7) << 4)));
    f32x4 o = (f32x4){0.f, 0.f, 0.f, 0.f};
    o = __builtin_amdgcn_mfma_f32_16x16x32_bf16(pa0, bv0, o, 0, 0, 0);
    o = __builtin_amdgcn_mfma_f32_16x16x32_bf16(pa1, bv1, o, 0, 0, 0);
#pragma unroll
    for (int j = 0; j < 4; ++j)
        ao[((size_t)(b * TQ + i0 + fg * 4 + j)) * HD + h * DHEAD + d] = f2bf(o[j]);
}

// ===========================================================================
extern "C" void kernel_launch(void* const* d_in, const int* in_sizes, int n_in,
                              void* d_out, int out_size, void* d_ws, size_t ws_size,
                              hipStream_t stream) {
    const float*   qo    = (const float*)d_in[0];
    const float*   kvo   = (const float*)d_in[1];
    const uint8_t* media = (const uint8_t*)d_in[2];
    const float*   ln_g  = (const float*)d_in[3];
    const float*   ln_b  = (const float*)d_in[4];
    const float*   Wq    = (const float*)d_in[5];
    const float*   Wkv   = (const float*)d_in[6];
    const float*   Wout  = (const float*)d_in[7];
    float* out = (float*)d_out;

    char* ws = (char*)d_ws;
    const size_t MB = 1u << 20;
    int* qt    = (int*)(ws);                  // 32 KB
    u16* Aq    = (u16*)(ws + 1  * MB);        // [1,17) MB  LN'd qo bf16 (dead after proj)
    u16* aob   = (u16*)(ws + 1  * MB);        // [1,9)  MB  attn out (reuses Aq region)
    u16* Akv   = (u16*)(ws + 17 * MB);        // [17,25) MB kvo bf16
    u16* Wqt   = (u16*)(ws + 25 * MB);        // 1 MB
    u16* Wkvt  = (u16*)(ws + 26 * MB);        // 2 MB
    u16* Woutt = (u16*)(ws + 28 * MB);        // 1 MB
    u16* qb    = (u16*)(ws + 29 * MB);        // [29,37) MB
    u16* kvb   = (u16*)(ws + 37 * MB);        // [37,45) MB

    prep_k<<<dim3(12292), dim3(256), 0, stream>>>(qo, kvo, media, ln_g, ln_b,
                                                  Wq, Wkv, Wout,
                                                  qt, Aq, Akv, Wqt, Wkvt, Woutt);
    proj_k<<<dim3(1024), dim3(256), 0, stream>>>(Aq, Wqt, qb, Akv, Wkvt, kvb);
    attn_k<<<dim3(TQ / 16, HEADS, BB), dim3(256), 0, stream>>>(qb, kvb, qt, aob);
    out_k<<<dim3(1024), dim3(256), 0, stream>>>(aob, Woutt, out);
}

// Round 5
// 170.139 us; speedup vs baseline: 1.0523x; 1.0523x over previous
//
#include <hip/hip_runtime.h>
#include <cstdint>
#include <cstddef>

// Problem constants (MaskedCrossAttention_27986006901343)
#define BB    4
#define TQ    2048
#define DIM   1024
#define TKV   16
#define NLAT  64
#define DLAT  1024
#define HEADS 8
#define DHEAD 64
#define LN_EPS 1e-5f
#define NKV   (TKV*NLAT)      // 1024 latents per batch
#define HD    (HEADS*DHEAD)   // 512

typedef unsigned short u16;
typedef __bf16 bf16x8 __attribute__((ext_vector_type(8)));
typedef float  f32x4  __attribute__((ext_vector_type(4)));

__device__ __forceinline__ u16 f2bf(float f) {      // RNE f32->bf16
    unsigned u = __builtin_bit_cast(unsigned, f);
    u += 0x7fffu + ((u >> 16) & 1u);
    return (u16)(u >> 16);
}
__device__ __forceinline__ void gl_lds16(const void* g, void* l) {
    __builtin_amdgcn_global_load_lds(
        (const __attribute__((address_space(1))) void*)g,
        (__attribute__((address_space(3))) void*)l, 16, 0, 0);
}

// ===========================================================================
// prep_k: fused qtime + LN(qo)->bf16 + cvt(kvo)->bf16 + 3 weight transposes.
// ===========================================================================
__device__ __forceinline__ void transpose_dev(const float* __restrict__ W,
                                              u16* __restrict__ Wt,
                                              int K, int N, int n0, int k0,
                                              float (*tile)[33]) {
    int t = threadIdx.x;
    int r = t >> 3, c4 = (t & 7) * 4;
    float4 v = *(const float4*)&W[(size_t)(k0 + r) * N + n0 + c4];
    tile[r][c4 + 0] = v.x; tile[r][c4 + 1] = v.y;
    tile[r][c4 + 2] = v.z; tile[r][c4 + 3] = v.w;
    __syncthreads();
    uint2 pk;
    pk.x = (unsigned)f2bf(tile[c4 + 0][r]) | ((unsigned)f2bf(tile[c4 + 1][r]) << 16);
    pk.y = (unsigned)f2bf(tile[c4 + 2][r]) | ((unsigned)f2bf(tile[c4 + 3][r]) << 16);
    *(uint2*)&Wt[(size_t)(n0 + r) * K + k0 + c4] = pk;
}

__global__ __launch_bounds__(256) void prep_k(
    const float* __restrict__ qo, const float* __restrict__ kvo,
    const uint8_t* __restrict__ media,
    const float* __restrict__ ln_g, const float* __restrict__ ln_b,
    const float* __restrict__ Wq, const float* __restrict__ Wkv,
    const float* __restrict__ Wout,
    int* __restrict__ qt, u16* __restrict__ Aq, u16* __restrict__ Akv,
    u16* __restrict__ Wqt, u16* __restrict__ Wkvt, u16* __restrict__ Woutt) {
    __shared__ int part[256];
    __shared__ int cnt_sh;
    __shared__ float sh[8];
    __shared__ float mu_s, rs_s;
    __shared__ float tile[32][33];
    int blk = blockIdx.x, t = threadIdx.x;

    if (blk < 4) {                    // ---- qtime (media dtype sniffed) ----
        int b = blk;
        int c = 0;
        for (int i = 0; i < 32; ++i) c += (media[t * 32 + i] != 0);
        part[t] = c;
        __syncthreads();
        if (t == 0) { int s = 0; for (int i = 0; i < 256; ++i) s += part[i]; cnt_sh = s; }
        __syncthreads();
        bool is_u8 = (cnt_sh >= 48);
        int vals[8];
        for (int i = 0; i < 8; ++i) {
            int idx = t * 8 + i;
            int m;
            if (is_u8) m = (media[(size_t)b * TQ + idx] != 0) ? 1 : 0;
            else       m = (((const uint32_t*)media)[(size_t)b * TQ + idx] != 0u) ? 1 : 0;
            vals[i] = m;
        }
        int loc = 0;
        for (int i = 0; i < 8; ++i) loc += vals[i];
        __syncthreads();
        part[t] = loc;
        __syncthreads();
        int pre = 0;
        for (int i = 0; i < t; ++i) pre += part[i];
        int run = pre;
        for (int i = 0; i < 8; ++i) {
            run += vals[i];
            qt[(size_t)b * TQ + t * 8 + i] = run;
        }
    } else if (blk < 4 + BB * TQ) {   // ---- LayerNorm + bf16 ----
        int row = blk - 4;
        float4 v = *(const float4*)(qo + (size_t)row * DIM + t * 4);
        float s  = v.x + v.y + v.z + v.w;
        float ss = v.x * v.x + v.y * v.y + v.z * v.z + v.w * v.w;
        for (int off = 32; off; off >>= 1) { s += __shfl_down(s, off); ss += __shfl_down(ss, off); }
        if ((t & 63) == 0) { sh[(t >> 6) * 2] = s; sh[(t >> 6) * 2 + 1] = ss; }
        __syncthreads();
        if (t == 0) {
            float S  = sh[0] + sh[2] + sh[4] + sh[6];
            float SS = sh[1] + sh[3] + sh[5] + sh[7];
            float m  = S * (1.0f / DIM);
            mu_s = m;
            rs_s = rsqrtf(SS * (1.0f / DIM) - m * m + LN_EPS);
        }
        __syncthreads();
        float mu = mu_s, rs = rs_s;
        float4 gv = *(const float4*)(ln_g + t * 4);
        float4 bv = *(const float4*)(ln_b + t * 4);
        float a0 = (v.x - mu) * rs * gv.x + bv.x;
        float a1 = (v.y - mu) * rs * gv.y + bv.y;
        float a2 = (v.z - mu) * rs * gv.z + bv.z;
        float a3 = (v.w - mu) * rs * gv.w + bv.w;
        uint2 pk;
        pk.x = (unsigned)f2bf(a0) | ((unsigned)f2bf(a1) << 16);
        pk.y = (unsigned)f2bf(a2) | ((unsigned)f2bf(a3) << 16);
        *(uint2*)(Aq + (size_t)row * DIM + t * 4) = pk;
    } else if (blk < 4 + BB * TQ + 2048) {   // ---- kvo f32->bf16 ----
        size_t i = (size_t)(blk - 4 - BB * TQ) * 256 + t;
        float4 a = ((const float4*)kvo)[i * 2];
        float4 b = ((const float4*)kvo)[i * 2 + 1];
        uint4 pk;
        pk.x = (unsigned)f2bf(a.x) | ((unsigned)f2bf(a.y) << 16);
        pk.y = (unsigned)f2bf(a.z) | ((unsigned)f2bf(a.w) << 16);
        pk.z = (unsigned)f2bf(b.x) | ((unsigned)f2bf(b.y) << 16);
        pk.w = (unsigned)f2bf(b.z) | ((unsigned)f2bf(b.w) << 16);
        ((uint4*)Akv)[i] = pk;
    } else if (blk < 10244 + 512) {   // ---- Wq^T ----
        int id = blk - 10244;
        transpose_dev(Wq, Wqt, DIM, HD, (id & 15) * 32, (id >> 4) * 32, tile);
    } else if (blk < 10756 + 1024) {  // ---- Wkv^T ----
        int id = blk - 10756;
        transpose_dev(Wkv, Wkvt, DLAT, 2 * HD, (id & 31) * 32, (id >> 5) * 32, tile);
    } else {                          // ---- Wout^T ----
        int id = blk - 11780;
        transpose_dev(Wout, Woutt, HD, DIM, (id & 31) * 32, (id >> 5) * 32, tile);
    }
}

// ===========================================================================
// bf16 MFMA GEMM body: C = A @ Bt^T * outscale.  128x128 tile, BK=32, 4 waves.
// T4 pipeline: 3 LDS buffers, 2-deep prefetch, counted s_waitcnt vmcnt(8)
// (never 0 in steady state) + raw s_barrier. Each S chunk = As(8KB)+Bs(8KB);
// 3 x 16KB = 48KB LDS. nt = K/32 must be >= 3 (here 16 or 32).
// ===========================================================================
template <typename CT>
__device__ __forceinline__ void gemm_body(const u16* __restrict__ A,
                                          const u16* __restrict__ Bt,
                                          CT* __restrict__ C,
                                          int M, int N, int K, float outscale,
                                          int bx, int by,
                                          u16* S0, u16* S1, u16* S2) {
    int t = threadIdx.x;
    int lane = t & 63, w = t >> 6;
    int wr = w >> 1, wc = w & 1;
    int fr = lane & 15, fg = lane >> 4;
    int row0 = by * 128, col0 = bx * 128;

    const u16* Ag = A  + (size_t)(row0 + (t >> 2)) * K + (t & 3) * 8;
    const u16* Bg = Bt + (size_t)(col0 + (t >> 2)) * K + (t & 3) * 8;
    size_t rstr = (size_t)64 * K;

    int aoff = (wr * 64 + fr) * 32 + fg * 8;          // u16 idx into As part
    int boff = 4096 + (wc * 64 + fr) * 32 + fg * 8;   // u16 idx into Bs part

    f32x4 acc[4][4];
#pragma unroll
    for (int mi = 0; mi < 4; ++mi)
#pragma unroll
        for (int ni = 0; ni < 4; ++ni) acc[mi][ni] = (f32x4){0.f, 0.f, 0.f, 0.f};

    auto stage = [&](u16* S, int kt) {                 // 4 x global_load_lds/thread
        char* al = (char*)S + w * 1024;
        char* bl = (char*)S + 8192 + w * 1024;
        int k0 = kt << 5;
        gl_lds16(Ag + k0,        al);
        gl_lds16(Ag + k0 + rstr, al + 4096);
        gl_lds16(Bg + k0,        bl);
        gl_lds16(Bg + k0 + rstr, bl + 4096);
    };
    auto compute = [&](const u16* S) {
        bf16x8 af[4], bfv[4];
#pragma unroll
        for (int mi = 0; mi < 4; ++mi) af[mi]  = *(const bf16x8*)(S + aoff + mi * 512);
#pragma unroll
        for (int ni = 0; ni < 4; ++ni) bfv[ni] = *(const bf16x8*)(S + boff + ni * 512);
#pragma unroll
        for (int mi = 0; mi < 4; ++mi)
#pragma unroll
            for (int ni = 0; ni < 4; ++ni)
                acc[mi][ni] = __builtin_amdgcn_mfma_f32_16x16x32_bf16(
                    af[mi], bfv[ni], acc[mi][ni], 0, 0, 0);
    };

    int nt = K >> 5;
    u16 *b0 = S0, *b1 = S1, *b2 = S2;
    stage(b0, 0);
    stage(b1, 1);
    for (int it = 0; it < nt - 2; ++it) {
        stage(b2, it + 2);                             // 2-deep prefetch
        asm volatile("s_waitcnt vmcnt(8)" ::: "memory");   // tile `it` landed
        __builtin_amdgcn_s_barrier();                  // all waves' quarters landed
        __builtin_amdgcn_sched_barrier(0);
        compute(b0);
        __builtin_amdgcn_sched_barrier(0);
        __builtin_amdgcn_s_barrier();                  // b0 reads done -> reusable
        u16* tmp = b0; b0 = b1; b1 = b2; b2 = tmp;
    }
    // epilogue: tiles nt-2 (b0) and nt-1 (b1) still in flight
    asm volatile("s_waitcnt vmcnt(4)" ::: "memory");
    __builtin_amdgcn_s_barrier();
    __builtin_amdgcn_sched_barrier(0);
    compute(b0);
    asm volatile("s_waitcnt vmcnt(0)" ::: "memory");
    __builtin_amdgcn_s_barrier();
    __builtin_amdgcn_sched_barrier(0);
    compute(b1);

#pragma unroll
    for (int mi = 0; mi < 4; ++mi) {
        int r0 = row0 + wr * 64 + mi * 16 + fg * 4;
#pragma unroll
        for (int ni = 0; ni < 4; ++ni) {
            int c = col0 + wc * 64 + ni * 16 + fr;
#pragma unroll
            for (int j = 0; j < 4; ++j) {
                float val = acc[mi][ni][j] * outscale;
                if constexpr (sizeof(CT) == 2) C[(size_t)(r0 + j) * N + c] = f2bf(val);
                else                           C[(size_t)(r0 + j) * N + c] = val;
            }
        }
    }
}

// Fused q-proj + kv-proj: 512 blocks (2/CU), 128x128 tiles.
__global__ __launch_bounds__(256) void proj_k(
    const u16* __restrict__ Aq,  const u16* __restrict__ Wqt,  u16* __restrict__ qb,
    const u16* __restrict__ Akv, const u16* __restrict__ Wkvt, u16* __restrict__ kvb) {
    __shared__ u16 S0[8192], S1[8192], S2[8192];   // 48KB
    int id = blockIdx.x;
    if (id < 256) {   // q-proj: M=8192 (by<64), N=512 (bx<4)
        gemm_body<u16>(Aq, Wqt, qb, BB * TQ, HD, DIM, 0.125f, id & 3, id >> 2,
                       S0, S1, S2);
    } else {          // kv-proj: M=4096 (by<32), N=1024 (bx<8)
        id -= 256;
        gemm_body<u16>(Akv, Wkvt, kvb, BB * NKV, 2 * HD, DLAT, 1.0f, id & 7, id >> 3,
                       S0, S1, S2);
    }
}

// out-proj: M=8192 (by<64), N=1024 (bx<8) -> 512 blocks.
__global__ __launch_bounds__(256) void out_k(
    const u16* __restrict__ aob, const u16* __restrict__ Woutt, float* __restrict__ out) {
    __shared__ u16 S0[8192], S1[8192], S2[8192];
    int id = blockIdx.x;
    gemm_body<float>(aob, Woutt, out, BB * TQ, DIM, HD, 1.0f, id & 7, id >> 3,
                     S0, S1, S2);
}

// ===========================================================================
// MFMA masked cross attention (round-3 proven). 16 q-rows x head x batch per
// block; QK^T + PV via mfma_16x16x32_bf16; XOR-swizzled LDS.
// ===========================================================================
__global__ __launch_bounds__(256) void attn_k(
    const u16* __restrict__ q,    // (B*TQ, 512) bf16, pre-scaled by 0.125
    const u16* __restrict__ kv,   // (B*NKV, 1024) bf16: k [0,512), v [512,1024)
    const int* __restrict__ qt,
    u16* __restrict__ ao) {       // (B*TQ, 512) bf16
    __shared__ u16 Ks[4096];      // swizzled [64][64]
    __shared__ u16 VT[4096];      // swizzled [64 d][64 lat]
    __shared__ u16 Ps[1024];      // swizzled [16][64]
    __shared__ float redm[4][16], reds[4][16];
    int i0 = blockIdx.x * 16;
    int h  = blockIdx.y;
    int b  = blockIdx.z;
    int t  = threadIdx.x;
    int lane = t & 63, w = t >> 6;
    int fr = lane & 15, fg = lane >> 4;

    int t0 = qt[(size_t)b * TQ + i0];
    if (t0 == 0) {
        int row = t >> 4, c = (t & 15) * 4;
        *(uint2*)&ao[((size_t)(b * TQ + i0 + row)) * HD + h * DHEAD + c] = make_uint2(0, 0);
        return;
    }
    int j0 = (t0 - 1) * 64;

    {   // stage K (swizzled row-major) + V (transposed, swizzled)
        int j = t >> 2, c16 = (t & 3) * 16;
        const u16* kvrow = kv + ((size_t)(b * NKV + j0 + j)) * (2 * HD) + h * DHEAD;
        uint4 k0v = *(const uint4*)(kvrow + c16);
        uint4 k1v = *(const uint4*)(kvrow + c16 + 8);
        uint4 v0v = *(const uint4*)(kvrow + HD + c16);
        uint4 v1v = *(const uint4*)(kvrow + HD + c16 + 8);
        int kb = j * 128 + c16 * 2;
        int swz = (j & 7) << 4;
        *(uint4*)((char*)Ks + ((kb)      ^ swz)) = k0v;
        *(uint4*)((char*)Ks + ((kb + 16) ^ swz)) = k1v;
        const u16* ve0 = (const u16*)&v0v;
        const u16* ve1 = (const u16*)&v1v;
#pragma unroll
        for (int e = 0; e < 8; ++e) {
            int d0 = c16 + e, d1 = c16 + 8 + e;
            *(u16*)((char*)VT + ((d0 * 128 + j * 2) ^ ((d0 & 7) << 4))) = ve0[e];
            *(u16*)((char*)VT + ((d1 * 128 + j * 2) ^ ((d1 & 7) << 4))) = ve1[e];
        }
    }
    const u16* qrow = q + ((size_t)(b * TQ + i0 + fr)) * HD + h * DHEAD + fg * 8;
    bf16x8 aq0 = *(const bf16x8*)(qrow);
    bf16x8 aq1 = *(const bf16x8*)(qrow + 32);
    __syncthreads();

    // QK^T: wave w computes S[16][w*16..w*16+16)
    int r = w * 16 + fr;
    bf16x8 bk0 = *(const bf16x8*)((char*)Ks + ((r * 128 + fg * 16)      ^ ((r & 7) << 4)));
    bf16x8 bk1 = *(const bf16x8*)((char*)Ks + ((r * 128 + 64 + fg * 16) ^ ((r & 7) << 4)));
    f32x4 s = (f32x4){0.f, 0.f, 0.f, 0.f};
    s = __builtin_amdgcn_mfma_f32_16x16x32_bf16(aq0, bk0, s, 0, 0, 0);
    s = __builtin_amdgcn_mfma_f32_16x16x32_bf16(aq1, bk1, s, 0, 0, 0);

    // softmax over 64 cols (4 waves x 16): intra-wave shfl + LDS cross-wave
    float mx[4];
#pragma unroll
    for (int j = 0; j < 4; ++j) {
        float m = s[j];
        for (int off = 1; off < 16; off <<= 1) m = fmaxf(m, __shfl_xor(m, off));
        mx[j] = m;
        redm[w][fg * 4 + j] = m;
    }
    __syncthreads();
    float p[4];
#pragma unroll
    for (int j = 0; j < 4; ++j) {
        int row = fg * 4 + j;
        float M = fmaxf(fmaxf(redm[0][row], redm[1][row]), fmaxf(redm[2][row], redm[3][row]));
        p[j] = __expf(s[j] - M);
        float sm = p[j];
        for (int off = 1; off < 16; off <<= 1) sm += __shfl_xor(sm, off);
        reds[w][row] = sm;
    }
    __syncthreads();
#pragma unroll
    for (int j = 0; j < 4; ++j) {
        int row = fg * 4 + j;
        float S = reds[0][row] + reds[1][row] + reds[2][row] + reds[3][row];
        u16 pb = f2bf(p[j] / S);
        *(u16*)((char*)Ps + ((row * 128 + (w * 16 + fr) * 2) ^ ((row & 7) << 4))) = pb;
    }
    __syncthreads();

    // PV: wave w computes O[16][w*16..w*16+16)
    bf16x8 pa0 = *(const bf16x8*)((char*)Ps + ((fr * 128 + fg * 16)      ^ ((fr & 7) << 4)));
    bf16x8 pa1 = *(const bf16x8*)((char*)Ps + ((fr * 128 + 64 + fg * 16) ^ ((fr & 7) << 4)));
    int d = w * 16 + fr;
    bf16x8 bv0 = *(const bf16x8*)((char*)VT + ((d * 128 + fg * 16)      ^ ((d & 7) << 4)));
    bf16x8 bv1 = *(const bf16x8*)((char*)VT + ((d * 128 + 64 + fg * 16) ^ ((d & 7) << 4)));
    f32x4 o = (f32x4){0.f, 0.f, 0.f, 0.f};
    o = __builtin_amdgcn_mfma_f32_16x16x32_bf16(pa0, bv0, o, 0, 0, 0);
    o = __builtin_amdgcn_mfma_f32_16x16x32_bf16(pa1, bv1, o, 0, 0, 0);
#pragma unroll
    for (int j = 0; j < 4; ++j)
        ao[((size_t)(b * TQ + i0 + fg * 4 + j)) * HD + h * DHEAD + d] = f2bf(o[j]);
}

// ===========================================================================
extern "C" void kernel_launch(void* const* d_in, const int* in_sizes, int n_in,
                              void* d_out, int out_size, void* d_ws, size_t ws_size,
                              hipStream_t stream) {
    const float*   qo    = (const float*)d_in[0];
    const float*   kvo   = (const float*)d_in[1];
    const uint8_t* media = (const uint8_t*)d_in[2];
    const float*   ln_g  = (const float*)d_in[3];
    const float*   ln_b  = (const float*)d_in[4];
    const float*   Wq    = (const float*)d_in[5];
    const float*   Wkv   = (const float*)d_in[6];
    const float*   Wout  = (const float*)d_in[7];
    float* out = (float*)d_out;

    char* ws = (char*)d_ws;
    const size_t MB = 1u << 20;
    int* qt    = (int*)(ws);                  // 32 KB
    u16* Aq    = (u16*)(ws + 1  * MB);        // [1,17) MB  LN'd qo bf16 (dead after proj)
    u16* aob   = (u16*)(ws + 1  * MB);        // [1,9)  MB  attn out (reuses Aq region)
    u16* Akv   = (u16*)(ws + 17 * MB);        // [17,25) MB kvo bf16
    u16* Wqt   = (u16*)(ws + 25 * MB);        // 1 MB
    u16* Wkvt  = (u16*)(ws + 26 * MB);        // 2 MB
    u16* Woutt = (u16*)(ws + 28 * MB);        // 1 MB
    u16* qb    = (u16*)(ws + 29 * MB);        // [29,37) MB
    u16* kvb   = (u16*)(ws + 37 * MB);        // [37,45) MB

    prep_k<<<dim3(12292), dim3(256), 0, stream>>>(qo, kvo, media, ln_g, ln_b,
                                                  Wq, Wkv, Wout,
                                                  qt, Aq, Akv, Wqt, Wkvt, Woutt);
    proj_k<<<dim3(512), dim3(256), 0, stream>>>(Aq, Wqt, qb, Akv, Wkvt, kvb);
    attn_k<<<dim3(TQ / 16, HEADS, BB), dim3(256), 0, stream>>>(qb, kvb, qt, aob);
    out_k<<<dim3(512), dim3(256), 0, stream>>>(aob, Woutt, out);
}